// Round 7
// baseline (124.614 us; speedup 1.0000x reference)
//
#include <hip/hip_runtime.h>
#include <hip/hip_fp16.h>
#include <cstdint>

#define N_RAND   20
#define N_GATES  28
#define E_DIM    512

struct OpsArg { int d[N_GATES]; };

// ---------- compile-time replication of np.random.RandomState(0) op list ----------
struct MT19937ce {
  uint32_t mt[624] = {};
  int mti = 0;
  constexpr void seed(uint32_t s){
    mt[0]=s;
    for(int i=1;i<624;i++) mt[i]=1812433253u*(mt[i-1]^(mt[i-1]>>30))+(uint32_t)i;
    mti=624;
  }
  constexpr uint32_t next(){
    if(mti>=624){
      for(int i=0;i<624;i++){
        uint32_t y=(mt[i]&0x80000000u)|(mt[(i+1)%624]&0x7fffffffu);
        mt[i]=mt[(i+397)%624]^(y>>1)^((y&1u)?0x9908b0dfu:0u);
      }
      mti=0;
    }
    uint32_t y=mt[mti++];
    y^=y>>11; y^=(y<<7)&0x9d2c5680u; y^=(y<<15)&0xefc60000u; y^=y>>18;
    return y;
  }
  constexpr uint32_t interval(uint32_t mx){
    if(!mx) return 0;
    uint32_t mask=mx; mask|=mask>>1; mask|=mask>>2; mask|=mask>>4; mask|=mask>>8; mask|=mask>>16;
    uint32_t v = next()&mask;
    while(v>mx) v = next()&mask;
    return v;
  }
};

constexpr OpsArg build_ops_ce(){
  MT19937ce rs; rs.seed(0);
  OpsArg o{};
  for(int i=0;i<N_RAND;i++){
    uint32_t k = rs.interval(3);
    if(k==3){
      int perm[8] = {0,1,2,3,4,5,6,7};
      for(int j=7;j>=1;j--){
        uint32_t t=rs.interval((uint32_t)j);
        int tmp=perm[j]; perm[j]=perm[t]; perm[t]=tmp;
      }
      o.d[i] = 3 | (perm[0]<<2) | (perm[1]<<5);
    } else {
      uint32_t w = rs.interval(7);
      o.d[i] = (int)k | ((int)w<<2);
    }
  }
  for(int i=0;i<8;i++) o.d[N_RAND+i] = 1 | (i<<2);
  return o;
}
inline constexpr OpsArg OPS = build_ops_ce();

// ---------- device helpers ----------
__device__ __forceinline__ float readlane_f(float v, int l){
  return __int_as_float(__builtin_amdgcn_readlane(__float_as_int(v), l));
}
template<int CTRL>
__device__ __forceinline__ float dpp_mov(float v){
  int s = __float_as_int(v);
  return __int_as_float(__builtin_amdgcn_update_dpp(s, s, CTRL, 0xF, 0xF, false));
}
// cross-lane xor<M> within 32-lane groups (M in {1,2,4,8,16})
template<int M>
__device__ __forceinline__ float xl(float v){
  if constexpr (M==1)      return dpp_mov<0xB1>(v);            // quad_perm [1,0,3,2]
  else if constexpr (M==2) return dpp_mov<0x4E>(v);            // quad_perm [2,3,0,1]
  else return __int_as_float(__builtin_amdgcn_ds_swizzle(__float_as_int(v), (M<<10)|0x1F));
}
// broadcast lane L (within each 32-lane group)
template<int L>
__device__ __forceinline__ float bcast(float v){
  return __int_as_float(__builtin_amdgcn_ds_swizzle(__float_as_int(v), L<<5));
}

typedef _Float16 v2h __attribute__((ext_vector_type(2)));
typedef _Float16 v8h __attribute__((ext_vector_type(8)));
typedef float    v4f __attribute__((ext_vector_type(4)));
union HU  { uint32_t u; v2h h; };

// ---------- fully specialized gate chain ----------
// Per token: amp idx = r*32 + l (l = lane&31). r bits (b2,b1,b0) = wires (0,1,2);
// l bits (b4..b0) = wires (3..7). 2 tokens per wave (lane>=32 -> token+1).
template<int G>
__device__ __forceinline__ void run_gates(float (&ar)[8], float (&ai)[8],
                                          const float (&sgn)[5], int l,
                                          float cv, float sv)
{
  if constexpr (G < N_GATES){
    constexpr int dd   = OPS.d[G];
    constexpr int kind = dd & 3;
    constexpr int wa   = (dd>>2) & 7;
    constexpr int wb   = (dd>>5) & 7;
    const float gc = readlane_f(cv, G);
    const float gs = readlane_f(sv, G);

    if constexpr (kind == 3){                       // ---- CNOT c=wa t=wb ----
      if constexpr (wa < 3 && wb < 3){              // reg-reg: pure register permute
        constexpr int Rc = 4>>wa, Rt = 4>>wb;
        #pragma unroll
        for (int r=0;r<8;r++){
          if ((r & Rc) && !(r & Rt)){
            float t0=ar[r]; ar[r]=ar[r|Rt]; ar[r|Rt]=t0;
            float t1=ai[r]; ai[r]=ai[r|Rt]; ai[r|Rt]=t1;
          }
        }
      } else if constexpr (wa < 3){                 // control reg, target lane
        constexpr int Rc = 4>>wa, Mt = 16>>(wb-3);
        #pragma unroll
        for (int r=0;r<8;r++){
          if (r & Rc){ ar[r]=xl<Mt>(ar[r]); ai[r]=xl<Mt>(ai[r]); }
        }
      } else if constexpr (wb < 3){                 // control lane, target reg
        constexpr int Mc = 16>>(wa-3), Rt = 4>>wb;
        const bool cb = (l & Mc) != 0;
        #pragma unroll
        for (int r=0;r<8;r++){
          if (!(r & Rt)){
            float alo=ar[r], ahi=ar[r|Rt];
            ar[r]    = cb ? ahi : alo;  ar[r|Rt] = cb ? alo : ahi;
            float blo=ai[r], bhi=ai[r|Rt];
            ai[r]    = cb ? bhi : blo;  ai[r|Rt] = cb ? blo : bhi;
          }
        }
      } else {                                      // both lane
        constexpr int Mc = 16>>(wa-3), Mt = 16>>(wb-3);
        const bool cb = (l & Mc) != 0;
        #pragma unroll
        for (int r=0;r<8;r++){
          float pr = xl<Mt>(ar[r]), pi_ = xl<Mt>(ai[r]);
          ar[r] = cb ? pr  : ar[r];
          ai[r] = cb ? pi_ : ai[r];
        }
      }
    } else if constexpr (kind == 2){                // ---- RZ wa ----
      if constexpr (wa < 3){
        constexpr int Rb = 4>>wa;
        #pragma unroll
        for (int r=0;r<8;r++){
          const float pim = (r & Rb) ? gs : -gs;
          float nr = gc*ar[r] - pim*ai[r];
          ai[r] = gc*ai[r] + pim*ar[r];
          ar[r] = nr;
        }
      } else {
        constexpr int SI = wa-3;
        const float pim = sgn[SI]*gs;
        #pragma unroll
        for (int r=0;r<8;r++){
          float nr = gc*ar[r] - pim*ai[r];
          ai[r] = gc*ai[r] + pim*ar[r];
          ar[r] = nr;
        }
      }
    } else if constexpr (kind == 1){                // ---- RY wa ----
      if constexpr (wa < 3){
        constexpr int Rb = 4>>wa;
        #pragma unroll
        for (int r=0;r<8;r++){
          if (!(r & Rb)){
            const int h = r|Rb;
            float lr=ar[r], li=ai[r], hr=ar[h], hii=ai[h];
            ar[r]=gc*lr - gs*hr;  ai[r]=gc*li - gs*hii;
            ar[h]=gs*lr + gc*hr;  ai[h]=gs*li + gc*hii;
          }
        }
      } else {
        constexpr int M = 16>>(wa-3), SI = wa-3;
        const float sg = sgn[SI]*gs;
        #pragma unroll
        for (int r=0;r<8;r++){
          float pr = xl<M>(ar[r]), pi_ = xl<M>(ai[r]);
          ar[r] = gc*ar[r] + sg*pr;
          ai[r] = gc*ai[r] + sg*pi_;
        }
      }
    } else {                                        // ---- RX wa ----
      if constexpr (wa < 3){
        constexpr int Rb = 4>>wa;
        #pragma unroll
        for (int r=0;r<8;r++){
          if (!(r & Rb)){
            const int h = r|Rb;
            float lr=ar[r], li=ai[r], hr=ar[h], hii=ai[h];
            ar[r]=gc*lr + gs*hii;  ai[r]=gc*li - gs*hr;
            ar[h]=gc*hr + gs*li;   ai[h]=gc*hii - gs*lr;
          }
        }
      } else {
        constexpr int M = 16>>(wa-3);
        #pragma unroll
        for (int r=0;r<8;r++){
          float pr = xl<M>(ar[r]), pi_ = xl<M>(ai[r]);
          ar[r] = gc*ar[r] + gs*pi_;
          ai[r] = gc*ai[r] - gs*pr;
        }
      }
    }
    run_gates<G+1>(ar, ai, sgn, l, cv, sv);
  }
}

// ================= fused kernel: circuit + W1 + MFMA GEMM, no workspace =================
// 256 threads = 4 waves; 8 tokens/block (2 per wave, same shape as the passing qcirc).
#define HSTR 72   // halfs per token row in LDS (64 used; 144B stride keeps b128 alignment)
__global__ __launch_bounds__(256)
void qffb_fused1(const float* __restrict__ x,
                 const float* __restrict__ ry_theta,
                 const float* __restrict__ rand_params,
                 const float* __restrict__ W1,
                 const float* __restrict__ b1,
                 const float* __restrict__ W2,
                 const float* __restrict__ b2,
                 float* __restrict__ out)
{
  __shared__ __half HLh[16*HSTR];     // rows 0..7 = tokens, rows 8..15 zeroed

  const int tid  = threadIdx.x;
  const int lane = tid & 63;
  const int l    = lane & 31;
  const int wave = tid >> 6;
  const int tl   = wave*2 + (lane>>5);            // token-local 0..7
  const int token = blockIdx.x*8 + tl;

  // zero MFMA rows 8..15 (halfs [576,1152) = u32 words [288,576))
  {
    uint32_t* Z = (uint32_t*)HLh;
    Z[288 + tid] = 0u;
    if (tid < 32) Z[544 + tid] = 0u;
  }

  // ---------------- phase 1: circuit (verbatim from the passing qcirc) ----------------
  float th = 0.f;
  if (lane < N_GATES)
    th = (lane < N_RAND) ? rand_params[lane] : ry_theta[lane - N_RAND];
  float cv, sv;
  __sincosf(0.5f*th, &sv, &cv);

  const float4 xa = *(const float4*)(x + (size_t)token*E_DIM);
  const float4 xb = *(const float4*)(x + (size_t)token*E_DIM + 4);
  float c[8], s[8];
  {
    float xs[8] = {xa.x, xa.y, xa.z, xa.w, xb.x, xb.y, xb.z, xb.w};
    #pragma unroll
    for (int w=0; w<8; ++w) __sincosf(0.5f*xs[w], &s[w], &c[w]);
  }

  float sgn[5];
  sgn[0] = (l&16) ? 1.f : -1.f;
  sgn[1] = (l& 8) ? 1.f : -1.f;
  sgn[2] = (l& 4) ? 1.f : -1.f;
  sgn[3] = (l& 2) ? 1.f : -1.f;
  sgn[4] = (l& 1) ? 1.f : -1.f;

  float lp = ((l&16)? s[3]:c[3]) * ((l&8)? s[4]:c[4]);
  lp *= ((l&4)? s[5]:c[5]) * ((l&2)? s[6]:c[6]);
  lp *= ((l&1)? s[7]:c[7]);
  const float q00=c[0]*c[1], q01=c[0]*s[1], q10=s[0]*c[1], q11=s[0]*s[1];
  const float c2lp=c[2]*lp, s2lp=s[2]*lp;
  float ar[8], ai[8];
  ar[0]=q00*c2lp; ar[1]=q00*s2lp; ar[2]=q01*c2lp; ar[3]=q01*s2lp;
  ar[4]=q10*c2lp; ar[5]=q10*s2lp; ar[6]=q11*c2lp; ar[7]=q11*s2lp;
  #pragma unroll
  for (int r=0;r<8;r++) ai[r]=0.f;

  run_gates<0>(ar, ai, sgn, l, cv, sv);

  // ---- measurement ----
  float p[8];
  #pragma unroll
  for (int r=0;r<8;r++) p[r] = ar[r]*ar[r] + ai[r]*ai[r];
  const float t1a=p[0]+p[1], t1b=p[2]+p[3], t1c=p[4]+p[5], t1d=p[6]+p[7];
  const float s0a=t1a+t1b, s0b=t1c+t1d;
  float P  = s0a + s0b;
  float e0 = s0a - s0b;
  float e1 = (t1a+t1c) - (t1b+t1d);
  float e2 = (p[0]-p[1])+(p[2]-p[3])+(p[4]-p[5])+(p[6]-p[7]);
  {
    float t;
    t=xl<1>(e0); e0+=t;  t=xl<1>(e1); e1+=t;  t=xl<1>(e2); e2+=t;
    t=xl<1>(P);  P = fmaf(-sgn[4], P, t);
    t=xl<2>(e0); e0+=t;  t=xl<2>(e1); e1+=t;  t=xl<2>(e2); e2+=t;
    t=xl<2>(P);  P = fmaf(-sgn[3], P, t);
    t=xl<4>(e0); e0+=t;  t=xl<4>(e1); e1+=t;  t=xl<4>(e2); e2+=t;
    t=xl<4>(P);  P = fmaf(-sgn[2], P, t);
    t=xl<8>(e0); e0+=t;  t=xl<8>(e1); e1+=t;  t=xl<8>(e2); e2+=t;
    t=xl<8>(P);  P = fmaf(-sgn[1], P, t);
    t=xl<16>(e0); e0+=t; t=xl<16>(e1); e1+=t; t=xl<16>(e2); e2+=t;
    t=xl<16>(P); P = fmaf(-sgn[0], P, t);
  }
  const float e3 = bcast<16>(P);
  const float e4 = bcast<8>(P);
  const float e5 = bcast<4>(P);
  const float e6 = bcast<2>(P);
  const float e7 = bcast<1>(P);

  // ---- h = relu(W1 @ e + b1): each lane computes h[2l], h[2l+1] -> LDS f16 ----
  const float4 wA0 = *(const float4*)(W1 + (size_t)(2*l)*8);
  const float4 wA1 = *(const float4*)(W1 + (size_t)(2*l)*8 + 4);
  const float4 wB0 = *(const float4*)(W1 + (size_t)(2*l+1)*8);
  const float4 wB1 = *(const float4*)(W1 + (size_t)(2*l+1)*8 + 4);
  const float2 bb  = *(const float2*)(b1 + 2*l);
  float h0 = bb.x + wA0.x*e0 + wA0.y*e1 + wA0.z*e2 + wA0.w*e3
                  + wA1.x*e4 + wA1.y*e5 + wA1.z*e6 + wA1.w*e7;
  float h1 = bb.y + wB0.x*e0 + wB0.y*e1 + wB0.z*e2 + wB0.w*e3
                  + wB1.x*e4 + wB1.y*e5 + wB1.z*e6 + wB1.w*e7;
  HU pk;
  pk.h = v2h{(_Float16)fmaxf(h0,0.f), (_Float16)fmaxf(h1,0.f)};
  *(uint32_t*)&HLh[(size_t)tl*HSTR + 2*l] = pk.u;

  __syncthreads();

  // ---------------- phase 2: out[8t x 512e] = H @ W2^T + b2 ----------------
  const int rr   = lane & 15;
  const int quad = lane >> 4;

  // A fragment: A[m=rr][k=quad*8+j] (rows 8..15 are zero)
  const v8h a0 = *(const v8h*)&HLh[rr*HSTR + quad*8];
  const v8h a1 = *(const v8h*)&HLh[rr*HSTR + 32 + quad*8];

  const int mt0 = blockIdx.x*8;
  #pragma unroll
  for (int j=0;j<8;++j){
    const int e = wave*128 + j*16 + rr;
    // B fragment from f32 W2, converted in-register (same pattern as passing R5)
    const float4 wa = *(const float4*)(W2 + (size_t)e*64 + quad*8);
    const float4 wb = *(const float4*)(W2 + (size_t)e*64 + quad*8 + 4);
    const float4 wc = *(const float4*)(W2 + (size_t)e*64 + 32 + quad*8);
    const float4 wd = *(const float4*)(W2 + (size_t)e*64 + 32 + quad*8 + 4);
    const v8h b0 = v8h{(_Float16)wa.x,(_Float16)wa.y,(_Float16)wa.z,(_Float16)wa.w,
                      (_Float16)wb.x,(_Float16)wb.y,(_Float16)wb.z,(_Float16)wb.w};
    const v8h b1v= v8h{(_Float16)wc.x,(_Float16)wc.y,(_Float16)wc.z,(_Float16)wc.w,
                      (_Float16)wd.x,(_Float16)wd.y,(_Float16)wd.z,(_Float16)wd.w};
    v4f acc = {0.f,0.f,0.f,0.f};
    acc = __builtin_amdgcn_mfma_f32_16x16x32_f16(a0, b0,  acc, 0, 0, 0);
    acc = __builtin_amdgcn_mfma_f32_16x16x32_f16(a1, b1v, acc, 0, 0, 0);
    // C/D: row(token-local) = quad*4+r2, col(e-in-tile) = rr; rows >=8 invalid
    if (quad < 2){
      const float bias = b2[e];
      #pragma unroll
      for (int r2=0;r2<4;r2++){
        const int t = mt0 + quad*4 + r2;
        out[(size_t)t*E_DIM + e] = acc[r2] + bias;
      }
    }
  }
}

extern "C" void kernel_launch(void* const* d_in, const int* in_sizes, int n_in,
                              void* d_out, int out_size, void* d_ws, size_t ws_size,
                              hipStream_t stream)
{
  (void)n_in; (void)out_size; (void)d_ws; (void)ws_size;
  const int ntok = in_sizes[0] / E_DIM;            // 16384

  qffb_fused1<<<ntok/8, 256, 0, stream>>>(
      (const float*)d_in[0],   // x
      (const float*)d_in[1],   // ry_theta
      (const float*)d_in[2],   // rand_params
      (const float*)d_in[3],   // W1
      (const float*)d_in[4],   // b1
      (const float*)d_in[5],   // W2
      (const float*)d_in[6],   // b2
      (float*)d_out);
}

// Round 10
// 122.799 us; speedup vs baseline: 1.0148x; 1.0148x over previous
//
#include <hip/hip_runtime.h>
#include <hip/hip_fp16.h>
#include <cstdint>

#define N_RAND   20
#define N_GATES  28
#define E_DIM    512

struct OpsArg { int d[N_GATES]; };

// ---------- compile-time replication of np.random.RandomState(0) op list ----------
struct MT19937ce {
  uint32_t mt[624] = {};
  int mti = 0;
  constexpr void seed(uint32_t s){
    mt[0]=s;
    for(int i=1;i<624;i++) mt[i]=1812433253u*(mt[i-1]^(mt[i-1]>>30))+(uint32_t)i;
    mti=624;
  }
  constexpr uint32_t next(){
    if(mti>=624){
      for(int i=0;i<624;i++){
        uint32_t y=(mt[i]&0x80000000u)|(mt[(i+1)%624]&0x7fffffffu);
        mt[i]=mt[(i+397)%624]^(y>>1)^((y&1u)?0x9908b0dfu:0u);
      }
      mti=0;
    }
    uint32_t y=mt[mti++];
    y^=y>>11; y^=(y<<7)&0x9d2c5680u; y^=(y<<15)&0xefc60000u; y^=y>>18;
    return y;
  }
  constexpr uint32_t interval(uint32_t mx){
    if(!mx) return 0;
    uint32_t mask=mx; mask|=mask>>1; mask|=mask>>2; mask|=mask>>4; mask|=mask>>8; mask|=mask>>16;
    uint32_t v = next()&mask;
    while(v>mx) v = next()&mask;
    return v;
  }
};

constexpr OpsArg build_ops_ce(){
  MT19937ce rs; rs.seed(0);
  OpsArg o{};
  for(int i=0;i<N_RAND;i++){
    uint32_t k = rs.interval(3);
    if(k==3){
      int perm[8] = {0,1,2,3,4,5,6,7};
      for(int j=7;j>=1;j--){
        uint32_t t=rs.interval((uint32_t)j);
        int tmp=perm[j]; perm[j]=perm[t]; perm[t]=tmp;
      }
      o.d[i] = 3 | (perm[0]<<2) | (perm[1]<<5);
    } else {
      uint32_t w = rs.interval(7);
      o.d[i] = (int)k | ((int)w<<2);
    }
  }
  for(int i=0;i<8;i++) o.d[N_RAND+i] = 1 | (i<<2);
  return o;
}
inline constexpr OpsArg OPS = build_ops_ce();

// ---------- device helpers ----------
__device__ __forceinline__ float readlane_f(float v, int l){
  return __int_as_float(__builtin_amdgcn_readlane(__float_as_int(v), l));
}
template<int CTRL>
__device__ __forceinline__ float dpp_mov(float v){
  int s = __float_as_int(v);
  return __int_as_float(__builtin_amdgcn_update_dpp(s, s, CTRL, 0xF, 0xF, false));
}
// cross-lane xor<M> within 32-lane groups (M in {1,2,4,8,16})
template<int M>
__device__ __forceinline__ float xl(float v){
  if constexpr (M==1)      return dpp_mov<0xB1>(v);            // quad_perm [1,0,3,2]
  else if constexpr (M==2) return dpp_mov<0x4E>(v);            // quad_perm [2,3,0,1]
  else return __int_as_float(__builtin_amdgcn_ds_swizzle(__float_as_int(v), (M<<10)|0x1F));
}
// broadcast lane L (within each 32-lane group)
template<int L>
__device__ __forceinline__ float bcast(float v){
  return __int_as_float(__builtin_amdgcn_ds_swizzle(__float_as_int(v), L<<5));
}

typedef _Float16 v2h __attribute__((ext_vector_type(2)));
typedef _Float16 v8h __attribute__((ext_vector_type(8)));
typedef float    v4f __attribute__((ext_vector_type(4)));
union HU  { uint32_t u; v2h h; };

// ---------- fully specialized gate chain ----------
// Per token: amp idx = r*32 + l (l = lane&31). r bits (b2,b1,b0) = wires (0,1,2);
// l bits (b4..b0) = wires (3..7). 2 tokens per wave (lane>=32 -> token+1).
template<int G>
__device__ __forceinline__ void run_gates(float (&ar)[8], float (&ai)[8],
                                          const float (&sgn)[5], int l,
                                          float cv, float sv)
{
  if constexpr (G < N_GATES){
    constexpr int dd   = OPS.d[G];
    constexpr int kind = dd & 3;
    constexpr int wa   = (dd>>2) & 7;
    constexpr int wb   = (dd>>5) & 7;
    const float gc = readlane_f(cv, G);
    const float gs = readlane_f(sv, G);

    if constexpr (kind == 3){                       // ---- CNOT c=wa t=wb ----
      if constexpr (wa < 3 && wb < 3){              // reg-reg: pure register permute
        constexpr int Rc = 4>>wa, Rt = 4>>wb;
        #pragma unroll
        for (int r=0;r<8;r++){
          if ((r & Rc) && !(r & Rt)){
            float t0=ar[r]; ar[r]=ar[r|Rt]; ar[r|Rt]=t0;
            float t1=ai[r]; ai[r]=ai[r|Rt]; ai[r|Rt]=t1;
          }
        }
      } else if constexpr (wa < 3){                 // control reg, target lane
        constexpr int Rc = 4>>wa, Mt = 16>>(wb-3);
        #pragma unroll
        for (int r=0;r<8;r++){
          if (r & Rc){ ar[r]=xl<Mt>(ar[r]); ai[r]=xl<Mt>(ai[r]); }
        }
      } else if constexpr (wb < 3){                 // control lane, target reg
        constexpr int Mc = 16>>(wa-3), Rt = 4>>wb;
        const bool cb = (l & Mc) != 0;
        #pragma unroll
        for (int r=0;r<8;r++){
          if (!(r & Rt)){
            float alo=ar[r], ahi=ar[r|Rt];
            ar[r]    = cb ? ahi : alo;  ar[r|Rt] = cb ? alo : ahi;
            float blo=ai[r], bhi=ai[r|Rt];
            ai[r]    = cb ? bhi : blo;  ai[r|Rt] = cb ? blo : bhi;
          }
        }
      } else {                                      // both lane
        constexpr int Mc = 16>>(wa-3), Mt = 16>>(wb-3);
        const bool cb = (l & Mc) != 0;
        #pragma unroll
        for (int r=0;r<8;r++){
          float pr = xl<Mt>(ar[r]), pi_ = xl<Mt>(ai[r]);
          ar[r] = cb ? pr  : ar[r];
          ai[r] = cb ? pi_ : ai[r];
        }
      }
    } else if constexpr (kind == 2){                // ---- RZ wa ----
      if constexpr (wa < 3){
        constexpr int Rb = 4>>wa;
        #pragma unroll
        for (int r=0;r<8;r++){
          const float pim = (r & Rb) ? gs : -gs;
          float nr = gc*ar[r] - pim*ai[r];
          ai[r] = gc*ai[r] + pim*ar[r];
          ar[r] = nr;
        }
      } else {
        constexpr int SI = wa-3;
        const float pim = sgn[SI]*gs;
        #pragma unroll
        for (int r=0;r<8;r++){
          float nr = gc*ar[r] - pim*ai[r];
          ai[r] = gc*ai[r] + pim*ar[r];
          ar[r] = nr;
        }
      }
    } else if constexpr (kind == 1){                // ---- RY wa ----
      if constexpr (wa < 3){
        constexpr int Rb = 4>>wa;
        #pragma unroll
        for (int r=0;r<8;r++){
          if (!(r & Rb)){
            const int h = r|Rb;
            float lr=ar[r], li=ai[r], hr=ar[h], hii=ai[h];
            ar[r]=gc*lr - gs*hr;  ai[r]=gc*li - gs*hii;
            ar[h]=gs*lr + gc*hr;  ai[h]=gs*li + gc*hii;
          }
        }
      } else {
        constexpr int M = 16>>(wa-3), SI = wa-3;
        const float sg = sgn[SI]*gs;
        #pragma unroll
        for (int r=0;r<8;r++){
          float pr = xl<M>(ar[r]), pi_ = xl<M>(ai[r]);
          ar[r] = gc*ar[r] + sg*pr;
          ai[r] = gc*ai[r] + sg*pi_;
        }
      }
    } else {                                        // ---- RX wa ----
      if constexpr (wa < 3){
        constexpr int Rb = 4>>wa;
        #pragma unroll
        for (int r=0;r<8;r++){
          if (!(r & Rb)){
            const int h = r|Rb;
            float lr=ar[r], li=ai[r], hr=ar[h], hii=ai[h];
            ar[r]=gc*lr + gs*hii;  ai[r]=gc*li - gs*hr;
            ar[h]=gc*hr + gs*li;   ai[h]=gc*hii - gs*lr;
          }
        }
      } else {
        constexpr int M = 16>>(wa-3);
        #pragma unroll
        for (int r=0;r<8;r++){
          float pr = xl<M>(ar[r]), pi_ = xl<M>(ai[r]);
          ar[r] = gc*ar[r] + gs*pi_;
          ai[r] = gc*ai[r] - gs*pr;
        }
      }
    }
    run_gates<G+1>(ar, ai, sgn, l, cv, sv);
  }
}

// ================= Kernel A: circuit + W1, TWO tokens per wave =================
// (byte-identical to the Round-3/Round-5 passing qcirc_kernel)
__global__ __launch_bounds__(256)
void qcirc_kernel(const float* __restrict__ x,
                  const float* __restrict__ ry_theta,
                  const float* __restrict__ rand_params,
                  const float* __restrict__ W1,
                  const float* __restrict__ b1,
                  __half* __restrict__ Hout)
{
  const int tid  = threadIdx.x;
  const int lane = tid & 63;
  const int l    = lane & 31;
  const int wave = tid >> 6;
  const int token = blockIdx.x*8 + wave*2 + (lane>>5);

  float th = 0.f;
  if (lane < N_GATES)
    th = (lane < N_RAND) ? rand_params[lane] : ry_theta[lane - N_RAND];
  float cv, sv;
  __sincosf(0.5f*th, &sv, &cv);

  const float4 xa = *(const float4*)(x + (size_t)token*E_DIM);
  const float4 xb = *(const float4*)(x + (size_t)token*E_DIM + 4);
  float c[8], s[8];
  {
    float xs[8] = {xa.x, xa.y, xa.z, xa.w, xb.x, xb.y, xb.z, xb.w};
    #pragma unroll
    for (int w=0; w<8; ++w) __sincosf(0.5f*xs[w], &s[w], &c[w]);
  }

  float sgn[5];
  sgn[0] = (l&16) ? 1.f : -1.f;
  sgn[1] = (l& 8) ? 1.f : -1.f;
  sgn[2] = (l& 4) ? 1.f : -1.f;
  sgn[3] = (l& 2) ? 1.f : -1.f;
  sgn[4] = (l& 1) ? 1.f : -1.f;

  float lp = ((l&16)? s[3]:c[3]) * ((l&8)? s[4]:c[4]);
  lp *= ((l&4)? s[5]:c[5]) * ((l&2)? s[6]:c[6]);
  lp *= ((l&1)? s[7]:c[7]);
  const float q00=c[0]*c[1], q01=c[0]*s[1], q10=s[0]*c[1], q11=s[0]*s[1];
  const float c2lp=c[2]*lp, s2lp=s[2]*lp;
  float ar[8], ai[8];
  ar[0]=q00*c2lp; ar[1]=q00*s2lp; ar[2]=q01*c2lp; ar[3]=q01*s2lp;
  ar[4]=q10*c2lp; ar[5]=q10*s2lp; ar[6]=q11*c2lp; ar[7]=q11*s2lp;
  #pragma unroll
  for (int r=0;r<8;r++) ai[r]=0.f;

  run_gates<0>(ar, ai, sgn, l, cv, sv);

  // ---- measurement ----
  float p[8];
  #pragma unroll
  for (int r=0;r<8;r++) p[r] = ar[r]*ar[r] + ai[r]*ai[r];
  const float t1a=p[0]+p[1], t1b=p[2]+p[3], t1c=p[4]+p[5], t1d=p[6]+p[7];
  const float s0a=t1a+t1b, s0b=t1c+t1d;
  float P  = s0a + s0b;
  float e0 = s0a - s0b;
  float e1 = (t1a+t1c) - (t1b+t1d);
  float e2 = (p[0]-p[1])+(p[2]-p[3])+(p[4]-p[5])+(p[6]-p[7]);
  {
    float t;
    t=xl<1>(e0); e0+=t;  t=xl<1>(e1); e1+=t;  t=xl<1>(e2); e2+=t;
    t=xl<1>(P);  P = fmaf(-sgn[4], P, t);
    t=xl<2>(e0); e0+=t;  t=xl<2>(e1); e1+=t;  t=xl<2>(e2); e2+=t;
    t=xl<2>(P);  P = fmaf(-sgn[3], P, t);
    t=xl<4>(e0); e0+=t;  t=xl<4>(e1); e1+=t;  t=xl<4>(e2); e2+=t;
    t=xl<4>(P);  P = fmaf(-sgn[2], P, t);
    t=xl<8>(e0); e0+=t;  t=xl<8>(e1); e1+=t;  t=xl<8>(e2); e2+=t;
    t=xl<8>(P);  P = fmaf(-sgn[1], P, t);
    t=xl<16>(e0); e0+=t; t=xl<16>(e1); e1+=t; t=xl<16>(e2); e2+=t;
    t=xl<16>(P); P = fmaf(-sgn[0], P, t);
  }
  const float e3 = bcast<16>(P);
  const float e4 = bcast<8>(P);
  const float e5 = bcast<4>(P);
  const float e6 = bcast<2>(P);
  const float e7 = bcast<1>(P);

  // ---- h = relu(W1 @ e + b1): each lane computes h[2l], h[2l+1] ----
  const float4 wA0 = *(const float4*)(W1 + (size_t)(2*l)*8);
  const float4 wA1 = *(const float4*)(W1 + (size_t)(2*l)*8 + 4);
  const float4 wB0 = *(const float4*)(W1 + (size_t)(2*l+1)*8);
  const float4 wB1 = *(const float4*)(W1 + (size_t)(2*l+1)*8 + 4);
  const float2 bb  = *(const float2*)(b1 + 2*l);
  float h0 = bb.x + wA0.x*e0 + wA0.y*e1 + wA0.z*e2 + wA0.w*e3
                  + wA1.x*e4 + wA1.y*e5 + wA1.z*e6 + wA1.w*e7;
  float h1 = bb.y + wB0.x*e0 + wB0.y*e1 + wB0.z*e2 + wB0.w*e3
                  + wB1.x*e4 + wB1.y*e5 + wB1.z*e6 + wB1.w*e7;
  HU pk;
  pk.h = v2h{(_Float16)fmaxf(h0,0.f), (_Float16)fmaxf(h1,0.f)};
  *(uint32_t*)((char*)Hout + ((size_t)token*64 + 2*l)*2) = pk.u;
}

// ================= Kernel B: out = H @ W2^T + b2 via f16 MFMA =================
// one 16-token stripe x 64 e per wave (4 tiles), coalesced epilogue via LDS.
#define TS_STRIDE 68
__global__ __launch_bounds__(256)
void mlp2_mfma4(const __half* __restrict__ Hh,
                const float* __restrict__ W2,
                const float* __restrict__ b2,
                float* __restrict__ out)
{
  __shared__ float Ts[4][16*TS_STRIDE];

  const int tid  = threadIdx.x;
  const int lane = tid & 63;
  const int wave = tid >> 6;
  const int wid  = blockIdx.x*4 + wave;
  const int mt   = wid >> 3;            // token tile (0..1023), 16 tokens
  const int ng   = wid & 7;             // e group (0..7), 64 e
  const int rr   = lane & 15;
  const int quad = lane >> 4;

  // A fragment: A[m=rr][k=quad*8+j] (same mapping Round 3 validated)
  const v8h a0 = *(const v8h*)(Hh + ((size_t)(mt*16 + rr))*64 + quad*8);
  const v8h a1 = *(const v8h*)(Hh + ((size_t)(mt*16 + rr))*64 + 32 + quad*8);

  #pragma unroll
  for (int j=0;j<4;++j){
    const int e = ng*64 + j*16 + rr;
    // B fragment from f32 W2, converted in-register (W2 is L2-resident)
    const float4 wa = *(const float4*)(W2 + (size_t)e*64 + quad*8);
    const float4 wb = *(const float4*)(W2 + (size_t)e*64 + quad*8 + 4);
    const float4 wc = *(const float4*)(W2 + (size_t)e*64 + 32 + quad*8);
    const float4 wd = *(const float4*)(W2 + (size_t)e*64 + 32 + quad*8 + 4);
    const v8h b0 = v8h{(_Float16)wa.x,(_Float16)wa.y,(_Float16)wa.z,(_Float16)wa.w,
                      (_Float16)wb.x,(_Float16)wb.y,(_Float16)wb.z,(_Float16)wb.w};
    const v8h b1 = v8h{(_Float16)wc.x,(_Float16)wc.y,(_Float16)wc.z,(_Float16)wc.w,
                      (_Float16)wd.x,(_Float16)wd.y,(_Float16)wd.z,(_Float16)wd.w};
    v4f acc = {0.f,0.f,0.f,0.f};
    acc = __builtin_amdgcn_mfma_f32_16x16x32_f16(a0, b0, acc, 0, 0, 0);
    acc = __builtin_amdgcn_mfma_f32_16x16x32_f16(a1, b1, acc, 0, 0, 0);
    // C/D: row(token) = quad*4+r2, col(e-in-tile) = rr  ->  stage in LDS
    #pragma unroll
    for (int r2=0;r2<4;r2++)
      Ts[wave][(quad*4+r2)*TS_STRIDE + j*16 + rr] = acc[r2];
  }

  __syncthreads();   // order LDS writes before cross-lane reads (per-wave tile, but be safe)

  // epilogue: lane L stores rows 4k+quad, e_local = rr*4..rr*4+3 -> 256B/row segments
  const float4 bias = *(const float4*)(b2 + ng*64 + rr*4);
  #pragma unroll
  for (int k=0;k<4;++k){
    const int row = 4*k + quad;
    float4 v = *(const float4*)&Ts[wave][row*TS_STRIDE + rr*4];
    v.x += bias.x; v.y += bias.y; v.z += bias.z; v.w += bias.w;
    const int t = mt*16 + row;
    *(float4*)(out + (size_t)t*E_DIM + ng*64 + rr*4) = v;
  }
}

extern "C" void kernel_launch(void* const* d_in, const int* in_sizes, int n_in,
                              void* d_out, int out_size, void* d_ws, size_t ws_size,
                              hipStream_t stream)
{
  (void)n_in; (void)out_size; (void)ws_size;
  const int ntok = in_sizes[0] / E_DIM;            // 16384
  __half* Hh = (__half*)d_ws;                      // ntok*64*2 = 2 MB scratch

  qcirc_kernel<<<ntok/8, 256, 0, stream>>>(
      (const float*)d_in[0],   // x
      (const float*)d_in[1],   // ry_theta
      (const float*)d_in[2],   // rand_params
      (const float*)d_in[3],   // W1
      (const float*)d_in[4],   // b1
      Hh);

  mlp2_mfma4<<<(ntok/16)*8/4, 256, 0, stream>>>(
      Hh,
      (const float*)d_in[5],   // W2
      (const float*)d_in[6],   // b2
      (float*)d_out);
}